// Round 1
// baseline (900.236 us; speedup 1.0000x reference)
//
#include <hip/hip_runtime.h>

#define T_TOK 2048
#define HD    2048
#define NE    32
#define ID    768
#define TOPK  8

typedef short bf16x8 __attribute__((ext_vector_type(8)));
typedef float f32x4  __attribute__((ext_vector_type(4)));

__device__ inline unsigned short f2bf(float f) {
    unsigned u = __builtin_bit_cast(unsigned, f);
    u += 0x7FFF + ((u >> 16) & 1);          // round-to-nearest-even
    return (unsigned short)(u >> 16);
}

// ---------------- X -> bf16 ----------------
__global__ void cvt_x(const float* __restrict__ x, unsigned short* __restrict__ x16) {
    int i = blockIdx.x * blockDim.x + threadIdx.x;       // one thread = 8 elems
    const float4* src = (const float4*)x + (size_t)i * 2;
    float4 a = src[0], b = src[1];
    uint4 r;
    r.x = (unsigned)f2bf(a.x) | ((unsigned)f2bf(a.y) << 16);
    r.y = (unsigned)f2bf(a.z) | ((unsigned)f2bf(a.w) << 16);
    r.z = (unsigned)f2bf(b.x) | ((unsigned)f2bf(b.y) << 16);
    r.w = (unsigned)f2bf(b.z) | ((unsigned)f2bf(b.w) << 16);
    *(uint4*)(x16 + (size_t)i * 8) = r;
}

// ---------------- router: logits -> softmax(topk cancel) -> top8 -> renorm ----------------
__global__ void router_kernel(const float* __restrict__ x, const float* __restrict__ wg,
                              int* __restrict__ topk_idx, float* __restrict__ topk_w,
                              int* __restrict__ counts) {
    int t = blockIdx.x;
    int tid = threadIdx.x;
    int e = tid & 31, seg = tid >> 5;                    // 32 experts x 8 H-segments
    const float* xr = x + (size_t)t * HD + seg * 256;
    const float* wp = wg + (size_t)(seg * 256) * NE + e;
    float acc = 0.f;
    #pragma unroll 4
    for (int j = 0; j < 256; ++j) acc += xr[j] * wp[j * NE];
    __shared__ float part[8][33];
    __shared__ float lg[32];
    part[seg][e] = acc;
    __syncthreads();
    if (tid < 32) {
        float s = 0.f;
        #pragma unroll
        for (int g = 0; g < 8; ++g) s += part[g][tid];
        lg[tid] = s;
    }
    __syncthreads();
    if (tid == 0) {
        float m = lg[0];
        for (int i = 1; i < 32; ++i) m = fmaxf(m, lg[i]);
        for (int i = 0; i < 32; ++i) lg[i] = __expf(lg[i] - m);
        // renormalized top-k weight = p_sel / sum(p_sel): softmax denom cancels
        int   idxs[TOPK]; float wv[TOPK]; float wsum = 0.f;
        #pragma unroll
        for (int k = 0; k < TOPK; ++k) {
            float best = -1.f; int bi = 0;
            for (int i = 0; i < 32; ++i) if (lg[i] > best) { best = lg[i]; bi = i; }
            idxs[k] = bi; wv[k] = best; wsum += best; lg[bi] = -1.f;
        }
        #pragma unroll
        for (int k = 0; k < TOPK; ++k) {
            topk_idx[t * TOPK + k] = idxs[k];
            topk_w[t * TOPK + k]   = wv[k] / wsum;
            atomicAdd(&counts[idxs[k]], 1);
        }
    }
}

__global__ void offsets_kernel(const int* __restrict__ counts, int* __restrict__ offsets,
                               int* __restrict__ cursor) {
    if (threadIdx.x == 0 && blockIdx.x == 0) {
        int run = 0;
        for (int e = 0; e < NE; ++e) { offsets[e] = run; cursor[e] = run; run += counts[e]; }
    }
}

__global__ void scatter_kernel(const int* __restrict__ topk_idx, int* __restrict__ cursor,
                               int* __restrict__ token_list) {
    int i = blockIdx.x * 256 + threadIdx.x;              // i encodes t*8+k
    int e = topk_idx[i];
    int pos = atomicAdd(&cursor[e], 1);
    token_list[pos] = i;
}

// ---------------- GEMM1: act = silu(X Wg) * (X Wu), per expert, gathered rows ----------------
__global__ __launch_bounds__(256, 2)
void gemm1_kernel(const unsigned short* __restrict__ X16,
                  const float* __restrict__ Wg, const float* __restrict__ Wu,
                  const int* __restrict__ token_list, const int* __restrict__ counts,
                  const int* __restrict__ offsets, unsigned short* __restrict__ act16) {
    int e = blockIdx.z, tt = blockIdx.y, it = blockIdx.x;
    int ne = counts[e];
    int row0 = tt * 128;
    if (row0 >= ne) return;
    int base = offsets[e];
    int i0 = it * 128;
    const float* wgw = Wg + (size_t)e * HD * ID;
    const float* wuw = Wu + (size_t)e * HD * ID;

    __shared__ __align__(16) unsigned short As[128][72];  // pad 72: 2-way read conflicts (free)
    __shared__ __align__(16) unsigned short Bg[128][72];  // stored [n][k] (transposed)
    __shared__ __align__(16) unsigned short Bu[128][72];
    __shared__ int rowTok[128];

    int tid = threadIdx.x;
    if (tid < 128) {
        int r = row0 + tid;
        rowTok[tid] = (r < ne) ? (token_list[base + r] >> 3) : 0;
    }
    __syncthreads();

    f32x4 accg[4][4], accu[4][4];
    #pragma unroll
    for (int m = 0; m < 4; ++m)
        #pragma unroll
        for (int n = 0; n < 4; ++n) {
            f32x4 z = {0.f, 0.f, 0.f, 0.f};
            accg[m][n] = z; accu[m][n] = z;
        }

    int lane = tid & 63, w = tid >> 6;
    int wm = w >> 1, wn = w & 1;                         // wave grid 2x2 (64t x 64i)
    int l15 = lane & 15, lhi = lane >> 4;

    int ar = tid >> 1;                                   // A stage: row
    int ac = (tid & 1) * 4;                              // chunk base (8-elem chunks)
    const unsigned short* aSrc = X16 + (size_t)rowTok[ar] * HD;

    for (int k0 = 0; k0 < HD; k0 += 64) {
        // stage A: gathered bf16 rows, 16B vector loads
        {
            const unsigned short* s = aSrc + k0;
            #pragma unroll
            for (int c = 0; c < 4; ++c)
                *(uint4*)&As[ar][(ac + c) * 8] = *(const uint4*)(s + (ac + c) * 8);
        }
        // stage B (gate+up): k-gather fp32 (coalesced across lanes), cvt, write [n][k]
        #pragma unroll
        for (int s4 = 0; s4 < 4; ++s4) {
            int u = tid + 256 * s4;
            int kc = u >> 7, ii = u & 127;
            const float* sg = wgw + (size_t)(k0 + kc * 8) * ID + i0 + ii;
            const float* su = wuw + (size_t)(k0 + kc * 8) * ID + i0 + ii;
            unsigned short tg[8], tu[8];
            #pragma unroll
            for (int q = 0; q < 8; ++q) { tg[q] = f2bf(sg[q * ID]); tu[q] = f2bf(su[q * ID]); }
            uint4 rg, ru;
            rg.x = (unsigned)tg[0] | ((unsigned)tg[1] << 16);
            rg.y = (unsigned)tg[2] | ((unsigned)tg[3] << 16);
            rg.z = (unsigned)tg[4] | ((unsigned)tg[5] << 16);
            rg.w = (unsigned)tg[6] | ((unsigned)tg[7] << 16);
            ru.x = (unsigned)tu[0] | ((unsigned)tu[1] << 16);
            ru.y = (unsigned)tu[2] | ((unsigned)tu[3] << 16);
            ru.z = (unsigned)tu[4] | ((unsigned)tu[5] << 16);
            ru.w = (unsigned)tu[6] | ((unsigned)tu[7] << 16);
            *(uint4*)&Bg[ii][kc * 8] = rg;
            *(uint4*)&Bu[ii][kc * 8] = ru;
        }
        __syncthreads();
        #pragma unroll
        for (int kk = 0; kk < 64; kk += 32) {
            int kl = kk + lhi * 8;
            bf16x8 a[4], bg[4], bu[4];
            #pragma unroll
            for (int m = 0; m < 4; ++m) a[m] = *(const bf16x8*)&As[wm * 64 + m * 16 + l15][kl];
            #pragma unroll
            for (int n = 0; n < 4; ++n) {
                bg[n] = *(const bf16x8*)&Bg[wn * 64 + n * 16 + l15][kl];
                bu[n] = *(const bf16x8*)&Bu[wn * 64 + n * 16 + l15][kl];
            }
            #pragma unroll
            for (int m = 0; m < 4; ++m)
                #pragma unroll
                for (int n = 0; n < 4; ++n) {
                    accg[m][n] = __builtin_amdgcn_mfma_f32_16x16x32_bf16(a[m], bg[n], accg[m][n], 0, 0, 0);
                    accu[m][n] = __builtin_amdgcn_mfma_f32_16x16x32_bf16(a[m], bu[n], accu[m][n], 0, 0, 0);
                }
        }
        __syncthreads();
    }

    // epilogue: silu(g)*u -> bf16 act (compact pair rows)
    #pragma unroll
    for (int m = 0; m < 4; ++m) {
        int rb = wm * 64 + m * 16 + lhi * 4;
        #pragma unroll
        for (int q = 0; q < 4; ++q) {
            int r = rb + q;
            if (row0 + r < ne) {
                size_t orow = (size_t)(base + row0 + r) * ID + i0 + wn * 64;
                #pragma unroll
                for (int n = 0; n < 4; ++n) {
                    float g = accg[m][n][q], uu = accu[m][n][q];
                    float a = g / (1.f + __expf(-g)) * uu;
                    act16[orow + n * 16 + l15] = f2bf(a);
                }
            }
        }
    }
}

// ---------------- GEMM2: out[t,:] += w * (act Wd), per expert ----------------
__global__ __launch_bounds__(256, 2)
void gemm2_kernel(const unsigned short* __restrict__ act16, const float* __restrict__ Wd,
                  const int* __restrict__ token_list, const int* __restrict__ counts,
                  const int* __restrict__ offsets, const float* __restrict__ topk_w,
                  float* __restrict__ out) {
    int e = blockIdx.z, tt = blockIdx.y, ht = blockIdx.x;
    int ne = counts[e];
    int row0 = tt * 128;
    if (row0 >= ne) return;
    int base = offsets[e];
    int h0 = ht * 128;
    const float* wdw = Wd + (size_t)e * ID * HD;

    __shared__ __align__(16) unsigned short As[128][72];
    __shared__ __align__(16) unsigned short Bs[128][72];
    __shared__ int   rowTok[128];
    __shared__ float rowW[128];

    int tid = threadIdx.x;
    if (tid < 128) {
        int r = row0 + tid;
        if (r < ne) { int v = token_list[base + r]; rowTok[tid] = v >> 3; rowW[tid] = topk_w[v]; }
        else        { rowTok[tid] = 0;              rowW[tid] = 0.f; }
    }
    __syncthreads();

    f32x4 acc[4][4];
    #pragma unroll
    for (int m = 0; m < 4; ++m)
        #pragma unroll
        for (int n = 0; n < 4; ++n) { f32x4 z = {0.f, 0.f, 0.f, 0.f}; acc[m][n] = z; }

    int lane = tid & 63, w = tid >> 6;
    int wm = w >> 1, wn = w & 1;
    int l15 = lane & 15, lhi = lane >> 4;

    int ar = tid >> 1, ac = (tid & 1) * 4;
    int pr = base + row0 + ar;
    if (pr > T_TOK * TOPK - 1) pr = T_TOK * TOPK - 1;    // clamp OOB tail reads
    const unsigned short* aSrc = act16 + (size_t)pr * ID;

    for (int k0 = 0; k0 < ID; k0 += 64) {
        #pragma unroll
        for (int c = 0; c < 4; ++c)
            *(uint4*)&As[ar][(ac + c) * 8] = *(const uint4*)(aSrc + k0 + (ac + c) * 8);
        #pragma unroll
        for (int s4 = 0; s4 < 4; ++s4) {
            int u = tid + 256 * s4;
            int kc = u >> 7, hh = u & 127;
            const float* sd = wdw + (size_t)(k0 + kc * 8) * HD + h0 + hh;
            unsigned short td[8];
            #pragma unroll
            for (int q = 0; q < 8; ++q) td[q] = f2bf(sd[q * HD]);
            uint4 rd;
            rd.x = (unsigned)td[0] | ((unsigned)td[1] << 16);
            rd.y = (unsigned)td[2] | ((unsigned)td[3] << 16);
            rd.z = (unsigned)td[4] | ((unsigned)td[5] << 16);
            rd.w = (unsigned)td[6] | ((unsigned)td[7] << 16);
            *(uint4*)&Bs[hh][kc * 8] = rd;
        }
        __syncthreads();
        #pragma unroll
        for (int kk = 0; kk < 64; kk += 32) {
            int kl = kk + lhi * 8;
            bf16x8 a[4], b[4];
            #pragma unroll
            for (int m = 0; m < 4; ++m) a[m] = *(const bf16x8*)&As[wm * 64 + m * 16 + l15][kl];
            #pragma unroll
            for (int n = 0; n < 4; ++n) b[n] = *(const bf16x8*)&Bs[wn * 64 + n * 16 + l15][kl];
            #pragma unroll
            for (int m = 0; m < 4; ++m)
                #pragma unroll
                for (int n = 0; n < 4; ++n)
                    acc[m][n] = __builtin_amdgcn_mfma_f32_16x16x32_bf16(a[m], b[n], acc[m][n], 0, 0, 0);
        }
        __syncthreads();
    }

    #pragma unroll
    for (int m = 0; m < 4; ++m) {
        int rb = wm * 64 + m * 16 + lhi * 4;
        #pragma unroll
        for (int q = 0; q < 4; ++q) {
            int r = rb + q;
            if (row0 + r < ne) {
                int tok = rowTok[r];
                float wgt = rowW[r];
                float* orow = out + (size_t)tok * HD + h0 + wn * 64;
                #pragma unroll
                for (int n = 0; n < 4; ++n)
                    atomicAdd(&orow[n * 16 + l15], acc[m][n][q] * wgt);
            }
        }
    }
}

extern "C" void kernel_launch(void* const* d_in, const int* in_sizes, int n_in,
                              void* d_out, int out_size, void* d_ws, size_t ws_size,
                              hipStream_t stream) {
    const float* x   = (const float*)d_in[0];
    const float* wg  = (const float*)d_in[1];
    const float* wgp = (const float*)d_in[2];
    const float* wup = (const float*)d_in[3];
    const float* wdp = (const float*)d_in[4];
    float* out = (float*)d_out;

    char* ws = (char*)d_ws;
    size_t off = 0;
    unsigned short* X16   = (unsigned short*)(ws + off); off += (size_t)T_TOK * HD * 2;        // 8 MB
    unsigned short* act16 = (unsigned short*)(ws + off); off += (size_t)T_TOK * TOPK * ID * 2; // 24 MB
    int*   topk_idx   = (int*)(ws + off);   off += T_TOK * TOPK * 4;
    float* topk_w     = (float*)(ws + off); off += T_TOK * TOPK * 4;
    int*   token_list = (int*)(ws + off);   off += T_TOK * TOPK * 4;
    int*   counts     = (int*)(ws + off);   off += 256;
    int*   offsets    = (int*)(ws + off);   off += 256;
    int*   cursor     = (int*)(ws + off);   off += 256;
    (void)ws_size; (void)in_sizes; (void)n_in; (void)out_size;

    hipMemsetAsync(counts, 0, 256, stream);
    hipMemsetAsync(d_out, 0, (size_t)T_TOK * HD * 4, stream);

    cvt_x<<<T_TOK * HD / (256 * 8), 256, 0, stream>>>(x, X16);
    router_kernel<<<T_TOK, 256, 0, stream>>>(x, wg, topk_idx, topk_w, counts);
    offsets_kernel<<<1, 64, 0, stream>>>(counts, offsets, cursor);
    scatter_kernel<<<T_TOK * TOPK / 256, 256, 0, stream>>>(topk_idx, cursor, token_list);
    gemm1_kernel<<<dim3(ID / 128, 16, NE), 256, 0, stream>>>(X16, wgp, wup, token_list, counts, offsets, act16);
    gemm2_kernel<<<dim3(HD / 128, 16, NE), 256, 0, stream>>>(act16, wdp, token_list, counts, offsets, topk_w, out);
}

// Round 2
// 632.393 us; speedup vs baseline: 1.4235x; 1.4235x over previous
//
#include <hip/hip_runtime.h>

#define T_TOK 2048
#define HD    2048
#define NE    32
#define ID    768
#define TOPK  8
#define NPAIR (T_TOK * TOPK)

typedef short bf16x8 __attribute__((ext_vector_type(8)));
typedef float f32x4  __attribute__((ext_vector_type(4)));

__device__ inline unsigned short f2bf(float f) {
    unsigned u = __builtin_bit_cast(unsigned, f);
    u += 0x7FFF + ((u >> 16) & 1);          // round-to-nearest-even
    return (unsigned short)(u >> 16);
}

__device__ inline void gload16(const void* g, void* l) {
    __builtin_amdgcn_global_load_lds(
        (const __attribute__((address_space(1))) unsigned*)g,
        (__attribute__((address_space(3))) unsigned*)l, 16, 0, 0);
}

// ---------------- X -> bf16 ----------------
__global__ void cvt_x(const float* __restrict__ x, unsigned short* __restrict__ x16) {
    int i = blockIdx.x * blockDim.x + threadIdx.x;       // one thread = 8 elems
    const float4* src = (const float4*)x + (size_t)i * 2;
    float4 a = src[0], b = src[1];
    uint4 r;
    r.x = (unsigned)f2bf(a.x) | ((unsigned)f2bf(a.y) << 16);
    r.y = (unsigned)f2bf(a.z) | ((unsigned)f2bf(a.w) << 16);
    r.z = (unsigned)f2bf(b.x) | ((unsigned)f2bf(b.y) << 16);
    r.w = (unsigned)f2bf(b.z) | ((unsigned)f2bf(b.w) << 16);
    *(uint4*)(x16 + (size_t)i * 8) = r;
}

// ---------------- weight transpose + cvt: [R][C] fp32 -> [C][R] bf16 (per expert) ----------------
__global__ void transpose_cvt(const float* __restrict__ in, unsigned short* __restrict__ out,
                              int R, int C) {
    int e = blockIdx.z;
    int r0 = blockIdx.y * 64, c0 = blockIdx.x * 64;
    const float* src = in + (size_t)e * R * C;
    unsigned short* dst = out + (size_t)e * R * C;
    __shared__ float tile[64][65];
    int tid = threadIdx.x;
    #pragma unroll
    for (int j = 0; j < 16; ++j) {
        int idx = tid + 256 * j;
        int rr = idx >> 6, cc = idx & 63;
        tile[rr][cc] = src[(size_t)(r0 + rr) * C + c0 + cc];
    }
    __syncthreads();
    #pragma unroll
    for (int j = 0; j < 8; ++j) {
        int idx = tid + 256 * j;
        int cc = idx >> 5, rr2 = (idx & 31) * 2;
        unsigned u = (unsigned)f2bf(tile[rr2][cc]) | ((unsigned)f2bf(tile[rr2 + 1][cc]) << 16);
        *(unsigned*)&dst[(size_t)(c0 + cc) * R + r0 + rr2] = u;
    }
}

// ---------------- router ----------------
__global__ void router_kernel(const float* __restrict__ x, const float* __restrict__ wg,
                              int* __restrict__ topk_idx, float* __restrict__ topk_w,
                              int* __restrict__ counts) {
    int t = blockIdx.x;
    int tid = threadIdx.x;
    int e = tid & 31, seg = tid >> 5;                    // 32 experts x 8 H-segments
    const float* xr = x + (size_t)t * HD + seg * 256;
    const float* wp = wg + (size_t)(seg * 256) * NE + e;
    float acc = 0.f;
    #pragma unroll 4
    for (int j = 0; j < 256; ++j) acc += xr[j] * wp[j * NE];
    __shared__ float part[8][33];
    __shared__ float lg[32];
    part[seg][e] = acc;
    __syncthreads();
    if (tid < 32) {
        float s = 0.f;
        #pragma unroll
        for (int g = 0; g < 8; ++g) s += part[g][tid];
        lg[tid] = s;
    }
    __syncthreads();
    if (tid == 0) {
        float m = lg[0];
        for (int i = 1; i < 32; ++i) m = fmaxf(m, lg[i]);
        for (int i = 0; i < 32; ++i) lg[i] = __expf(lg[i] - m);
        int   idxs[TOPK]; float wv[TOPK]; float wsum = 0.f;
        #pragma unroll
        for (int k = 0; k < TOPK; ++k) {
            float best = -1.f; int bi = 0;
            for (int i = 0; i < 32; ++i) if (lg[i] > best) { best = lg[i]; bi = i; }
            idxs[k] = bi; wv[k] = best; wsum += best; lg[bi] = -1.f;
        }
        #pragma unroll
        for (int k = 0; k < TOPK; ++k) {
            topk_idx[t * TOPK + k] = idxs[k];
            topk_w[t * TOPK + k]   = wv[k] / wsum;
            atomicAdd(&counts[idxs[k]], 1);
        }
    }
}

__global__ void offsets_kernel(const int* __restrict__ counts, int* __restrict__ offsets,
                               int* __restrict__ cursor) {
    if (threadIdx.x == 0 && blockIdx.x == 0) {
        int run = 0;
        for (int e = 0; e < NE; ++e) { offsets[e] = run; cursor[e] = run; run += counts[e]; }
    }
}

__global__ void scatter_kernel(const int* __restrict__ topk_idx, int* __restrict__ cursor,
                               int* __restrict__ token_list) {
    int i = blockIdx.x * 256 + threadIdx.x;
    int e = topk_idx[i];
    int pos = atomicAdd(&cursor[e], 1);
    token_list[pos] = i;
}

// ================= FAST PATH: bf16 pre-transposed weights, global_load_lds, swizzled =================

// GEMM1: act = silu(X Wg) * (X Wu); A gathered token rows, B rows = i-cols (k-contiguous)
__global__ __launch_bounds__(256, 2)
void gemm1_kernel(const unsigned short* __restrict__ X16,
                  const unsigned short* __restrict__ WG, const unsigned short* __restrict__ WU,
                  const int* __restrict__ token_list, const int* __restrict__ counts,
                  const int* __restrict__ offsets, unsigned short* __restrict__ act16) {
    int e = blockIdx.z, tt = blockIdx.y, it = blockIdx.x;
    int ne = counts[e];
    int row0 = tt * 128;
    if (row0 >= ne) return;
    int base = offsets[e];
    int i0 = it * 128;

    __shared__ __align__(16) unsigned short As[128 * 64];   // linear [row][64k], 128B rows
    __shared__ __align__(16) unsigned short Bg[128 * 64];
    __shared__ __align__(16) unsigned short Bu[128 * 64];
    __shared__ int rowTok[128];

    int tid = threadIdx.x;
    if (tid < 128) {
        int r = row0 + tid;
        rowTok[tid] = (r < ne) ? (token_list[base + r] >> 3) : 0;
    }
    __syncthreads();

    int lane = tid & 63, w = tid >> 6;
    int sub = lane & 7, lrow = lane >> 3;

    // per-thread swizzled global base pointers: instr q=w*4+c covers rows q*8..q*8+7
    const unsigned short* aP[4]; const unsigned short* gP[4]; const unsigned short* uP[4];
    #pragma unroll
    for (int c = 0; c < 4; ++c) {
        int q = w * 4 + c;
        int r = q * 8 + lrow;
        int chunk = (sub ^ (r & 7)) * 8;                  // swizzled 16B-chunk (elements)
        aP[c] = X16 + (size_t)rowTok[r] * HD + chunk;
        gP[c] = WG + ((size_t)e * ID + i0 + r) * HD + chunk;
        uP[c] = WU + ((size_t)e * ID + i0 + r) * HD + chunk;
    }

    f32x4 accg[4][4], accu[4][4];
    #pragma unroll
    for (int m = 0; m < 4; ++m)
        #pragma unroll
        for (int n = 0; n < 4; ++n) {
            f32x4 z = {0.f, 0.f, 0.f, 0.f};
            accg[m][n] = z; accu[m][n] = z;
        }

    int wm = w >> 1, wn = w & 1, l15 = lane & 15, lhi = lane >> 4;
    const bf16x8* Af = (const bf16x8*)As;
    const bf16x8* Gf = (const bf16x8*)Bg;
    const bf16x8* Uf = (const bf16x8*)Bu;

    for (int k0 = 0; k0 < HD; k0 += 64) {
        #pragma unroll
        for (int c = 0; c < 4; ++c) {
            int q = w * 4 + c;
            gload16(aP[c] + k0, (char*)As + q * 1024);
            gload16(gP[c] + k0, (char*)Bg + q * 1024);
            gload16(uP[c] + k0, (char*)Bu + q * 1024);
        }
        __syncthreads();
        #pragma unroll
        for (int ks = 0; ks < 2; ++ks) {
            int cc = ks * 4 + lhi;                        // 16B-chunk index (unswizzled)
            bf16x8 a[4], bg[4], bu[4];
            #pragma unroll
            for (int m = 0; m < 4; ++m) { int r = wm * 64 + m * 16 + l15; a[m] = Af[r * 8 + (cc ^ (r & 7))]; }
            #pragma unroll
            for (int n = 0; n < 4; ++n) {
                int r = wn * 64 + n * 16 + l15;
                bg[n] = Gf[r * 8 + (cc ^ (r & 7))];
                bu[n] = Uf[r * 8 + (cc ^ (r & 7))];
            }
            #pragma unroll
            for (int m = 0; m < 4; ++m)
                #pragma unroll
                for (int n = 0; n < 4; ++n) {
                    accg[m][n] = __builtin_amdgcn_mfma_f32_16x16x32_bf16(a[m], bg[n], accg[m][n], 0, 0, 0);
                    accu[m][n] = __builtin_amdgcn_mfma_f32_16x16x32_bf16(a[m], bu[n], accu[m][n], 0, 0, 0);
                }
        }
        __syncthreads();
    }

    #pragma unroll
    for (int m = 0; m < 4; ++m) {
        int rb = wm * 64 + m * 16 + lhi * 4;
        #pragma unroll
        for (int q = 0; q < 4; ++q) {
            int r = rb + q;
            if (row0 + r < ne) {
                size_t orow = (size_t)(base + row0 + r) * ID + i0 + wn * 64;
                #pragma unroll
                for (int n = 0; n < 4; ++n) {
                    float g = accg[m][n][q], uu = accu[m][n][q];
                    float a = g / (1.f + __expf(-g)) * uu;
                    act16[orow + n * 16 + l15] = f2bf(a);
                }
            }
        }
    }
}

// GEMM2: out[t,:] += w * (act Wd); A compact pair rows, B rows = h-cols (k=i contiguous)
__global__ __launch_bounds__(256, 2)
void gemm2_kernel(const unsigned short* __restrict__ act16, const unsigned short* __restrict__ WD,
                  const int* __restrict__ token_list, const int* __restrict__ counts,
                  const int* __restrict__ offsets, const float* __restrict__ topk_w,
                  float* __restrict__ out) {
    int e = blockIdx.z, tt = blockIdx.y, ht = blockIdx.x;
    int ne = counts[e];
    int row0 = tt * 128;
    if (row0 >= ne) return;
    int base = offsets[e];
    int h0 = ht * 128;

    __shared__ __align__(16) unsigned short As[128 * 64];
    __shared__ __align__(16) unsigned short Bs[128 * 64];
    __shared__ int   rowTok[128];
    __shared__ float rowW[128];

    int tid = threadIdx.x;
    if (tid < 128) {
        int r = row0 + tid;
        if (r < ne) { int v = token_list[base + r]; rowTok[tid] = v >> 3; rowW[tid] = topk_w[v]; }
        else        { rowTok[tid] = 0;              rowW[tid] = 0.f; }
    }
    __syncthreads();

    int lane = tid & 63, w = tid >> 6;
    int sub = lane & 7, lrow = lane >> 3;

    const unsigned short* aP[4]; const unsigned short* bP[4];
    #pragma unroll
    for (int c = 0; c < 4; ++c) {
        int q = w * 4 + c;
        int r = q * 8 + lrow;
        int chunk = (sub ^ (r & 7)) * 8;
        int pr = base + row0 + r;
        if (pr > NPAIR - 1) pr = NPAIR - 1;
        aP[c] = act16 + (size_t)pr * ID + chunk;
        bP[c] = WD + ((size_t)e * HD + h0 + r) * ID + chunk;
    }

    f32x4 acc[4][4];
    #pragma unroll
    for (int m = 0; m < 4; ++m)
        #pragma unroll
        for (int n = 0; n < 4; ++n) { f32x4 z = {0.f, 0.f, 0.f, 0.f}; acc[m][n] = z; }

    int wm = w >> 1, wn = w & 1, l15 = lane & 15, lhi = lane >> 4;
    const bf16x8* Af = (const bf16x8*)As;
    const bf16x8* Bf = (const bf16x8*)Bs;

    for (int k0 = 0; k0 < ID; k0 += 64) {
        #pragma unroll
        for (int c = 0; c < 4; ++c) {
            int q = w * 4 + c;
            gload16(aP[c] + k0, (char*)As + q * 1024);
            gload16(bP[c] + k0, (char*)Bs + q * 1024);
        }
        __syncthreads();
        #pragma unroll
        for (int ks = 0; ks < 2; ++ks) {
            int cc = ks * 4 + lhi;
            bf16x8 a[4], b[4];
            #pragma unroll
            for (int m = 0; m < 4; ++m) { int r = wm * 64 + m * 16 + l15; a[m] = Af[r * 8 + (cc ^ (r & 7))]; }
            #pragma unroll
            for (int n = 0; n < 4; ++n) { int r = wn * 64 + n * 16 + l15; b[n] = Bf[r * 8 + (cc ^ (r & 7))]; }
            #pragma unroll
            for (int m = 0; m < 4; ++m)
                #pragma unroll
                for (int n = 0; n < 4; ++n)
                    acc[m][n] = __builtin_amdgcn_mfma_f32_16x16x32_bf16(a[m], b[n], acc[m][n], 0, 0, 0);
        }
        __syncthreads();
    }

    #pragma unroll
    for (int m = 0; m < 4; ++m) {
        int rb = wm * 64 + m * 16 + lhi * 4;
        #pragma unroll
        for (int q = 0; q < 4; ++q) {
            int r = rb + q;
            if (row0 + r < ne) {
                int tok = rowTok[r];
                float wgt = rowW[r];
                float* orow = out + (size_t)tok * HD + h0 + wn * 64;
                #pragma unroll
                for (int n = 0; n < 4; ++n)
                    atomicAdd(&orow[n * 16 + l15], acc[m][n][q] * wgt);
            }
        }
    }
}

// ================= FALLBACK PATH (ws too small): round-1 fp32-gather GEMMs =================
__global__ __launch_bounds__(256, 2)
void gemm1_fb(const unsigned short* __restrict__ X16,
              const float* __restrict__ Wg, const float* __restrict__ Wu,
              const int* __restrict__ token_list, const int* __restrict__ counts,
              const int* __restrict__ offsets, unsigned short* __restrict__ act16) {
    int e = blockIdx.z, tt = blockIdx.y, it = blockIdx.x;
    int ne = counts[e];
    int row0 = tt * 128;
    if (row0 >= ne) return;
    int base = offsets[e];
    int i0 = it * 128;
    const float* wgw = Wg + (size_t)e * HD * ID;
    const float* wuw = Wu + (size_t)e * HD * ID;
    __shared__ __align__(16) unsigned short As[128][72];
    __shared__ __align__(16) unsigned short Bg[128][72];
    __shared__ __align__(16) unsigned short Bu[128][72];
    __shared__ int rowTok[128];
    int tid = threadIdx.x;
    if (tid < 128) {
        int r = row0 + tid;
        rowTok[tid] = (r < ne) ? (token_list[base + r] >> 3) : 0;
    }
    __syncthreads();
    f32x4 accg[4][4], accu[4][4];
    #pragma unroll
    for (int m = 0; m < 4; ++m)
        #pragma unroll
        for (int n = 0; n < 4; ++n) { f32x4 z = {0.f,0.f,0.f,0.f}; accg[m][n] = z; accu[m][n] = z; }
    int lane = tid & 63, w = tid >> 6;
    int wm = w >> 1, wn = w & 1, l15 = lane & 15, lhi = lane >> 4;
    int ar = tid >> 1, ac = (tid & 1) * 4;
    const unsigned short* aSrc = X16 + (size_t)rowTok[ar] * HD;
    for (int k0 = 0; k0 < HD; k0 += 64) {
        {
            const unsigned short* s = aSrc + k0;
            #pragma unroll
            for (int c = 0; c < 4; ++c)
                *(uint4*)&As[ar][(ac + c) * 8] = *(const uint4*)(s + (ac + c) * 8);
        }
        #pragma unroll
        for (int s4 = 0; s4 < 4; ++s4) {
            int u = tid + 256 * s4;
            int kc = u >> 7, ii = u & 127;
            const float* sg = wgw + (size_t)(k0 + kc * 8) * ID + i0 + ii;
            const float* su = wuw + (size_t)(k0 + kc * 8) * ID + i0 + ii;
            unsigned short tg[8], tu[8];
            #pragma unroll
            for (int q = 0; q < 8; ++q) { tg[q] = f2bf(sg[q * ID]); tu[q] = f2bf(su[q * ID]); }
            uint4 rg, ru;
            rg.x = (unsigned)tg[0] | ((unsigned)tg[1] << 16);
            rg.y = (unsigned)tg[2] | ((unsigned)tg[3] << 16);
            rg.z = (unsigned)tg[4] | ((unsigned)tg[5] << 16);
            rg.w = (unsigned)tg[6] | ((unsigned)tg[7] << 16);
            ru.x = (unsigned)tu[0] | ((unsigned)tu[1] << 16);
            ru.y = (unsigned)tu[2] | ((unsigned)tu[3] << 16);
            ru.z = (unsigned)tu[4] | ((unsigned)tu[5] << 16);
            ru.w = (unsigned)tu[6] | ((unsigned)tu[7] << 16);
            *(uint4*)&Bg[ii][kc * 8] = rg;
            *(uint4*)&Bu[ii][kc * 8] = ru;
        }
        __syncthreads();
        #pragma unroll
        for (int kk = 0; kk < 64; kk += 32) {
            int kl = kk + lhi * 8;
            bf16x8 a[4], bg[4], bu[4];
            #pragma unroll
            for (int m = 0; m < 4; ++m) a[m] = *(const bf16x8*)&As[wm * 64 + m * 16 + l15][kl];
            #pragma unroll
            for (int n = 0; n < 4; ++n) {
                bg[n] = *(const bf16x8*)&Bg[wn * 64 + n * 16 + l15][kl];
                bu[n] = *(const bf16x8*)&Bu[wn * 64 + n * 16 + l15][kl];
            }
            #pragma unroll
            for (int m = 0; m < 4; ++m)
                #pragma unroll
                for (int n = 0; n < 4; ++n) {
                    accg[m][n] = __builtin_amdgcn_mfma_f32_16x16x32_bf16(a[m], bg[n], accg[m][n], 0, 0, 0);
                    accu[m][n] = __builtin_amdgcn_mfma_f32_16x16x32_bf16(a[m], bu[n], accu[m][n], 0, 0, 0);
                }
        }
        __syncthreads();
    }
    #pragma unroll
    for (int m = 0; m < 4; ++m) {
        int rb = wm * 64 + m * 16 + lhi * 4;
        #pragma unroll
        for (int q = 0; q < 4; ++q) {
            int r = rb + q;
            if (row0 + r < ne) {
                size_t orow = (size_t)(base + row0 + r) * ID + i0 + wn * 64;
                #pragma unroll
                for (int n = 0; n < 4; ++n) {
                    float g = accg[m][n][q], uu = accu[m][n][q];
                    float a = g / (1.f + __expf(-g)) * uu;
                    act16[orow + n * 16 + l15] = f2bf(a);
                }
            }
        }
    }
}

__global__ __launch_bounds__(256, 2)
void gemm2_fb(const unsigned short* __restrict__ act16, const float* __restrict__ Wd,
              const int* __restrict__ token_list, const int* __restrict__ counts,
              const int* __restrict__ offsets, const float* __restrict__ topk_w,
              float* __restrict__ out) {
    int e = blockIdx.z, tt = blockIdx.y, ht = blockIdx.x;
    int ne = counts[e];
    int row0 = tt * 128;
    if (row0 >= ne) return;
    int base = offsets[e];
    int h0 = ht * 128;
    const float* wdw = Wd + (size_t)e * ID * HD;
    __shared__ __align__(16) unsigned short As[128][72];
    __shared__ __align__(16) unsigned short Bs[128][72];
    __shared__ int   rowTok[128];
    __shared__ float rowW[128];
    int tid = threadIdx.x;
    if (tid < 128) {
        int r = row0 + tid;
        if (r < ne) { int v = token_list[base + r]; rowTok[tid] = v >> 3; rowW[tid] = topk_w[v]; }
        else        { rowTok[tid] = 0;              rowW[tid] = 0.f; }
    }
    __syncthreads();
    f32x4 acc[4][4];
    #pragma unroll
    for (int m = 0; m < 4; ++m)
        #pragma unroll
        for (int n = 0; n < 4; ++n) { f32x4 z = {0.f,0.f,0.f,0.f}; acc[m][n] = z; }
    int lane = tid & 63, w = tid >> 6;
    int wm = w >> 1, wn = w & 1, l15 = lane & 15, lhi = lane >> 4;
    int ar = tid >> 1, ac = (tid & 1) * 4;
    int pr = base + row0 + ar;
    if (pr > NPAIR - 1) pr = NPAIR - 1;
    const unsigned short* aSrc = act16 + (size_t)pr * ID;
    for (int k0 = 0; k0 < ID; k0 += 64) {
        #pragma unroll
        for (int c = 0; c < 4; ++c)
            *(uint4*)&As[ar][(ac + c) * 8] = *(const uint4*)(aSrc + k0 + (ac + c) * 8);
        #pragma unroll
        for (int s4 = 0; s4 < 4; ++s4) {
            int u = tid + 256 * s4;
            int kc = u >> 7, hh = u & 127;
            const float* sd = wdw + (size_t)(k0 + kc * 8) * HD + h0 + hh;
            unsigned short td[8];
            #pragma unroll
            for (int q = 0; q < 8; ++q) td[q] = f2bf(sd[q * HD]);
            uint4 rd;
            rd.x = (unsigned)td[0] | ((unsigned)td[1] << 16);
            rd.y = (unsigned)td[2] | ((unsigned)td[3] << 16);
            rd.z = (unsigned)td[4] | ((unsigned)td[5] << 16);
            rd.w = (unsigned)td[6] | ((unsigned)td[7] << 16);
            *(uint4*)&Bs[hh][kc * 8] = rd;
        }
        __syncthreads();
        #pragma unroll
        for (int kk = 0; kk < 64; kk += 32) {
            int kl = kk + lhi * 8;
            bf16x8 a[4], b[4];
            #pragma unroll
            for (int m = 0; m < 4; ++m) a[m] = *(const bf16x8*)&As[wm * 64 + m * 16 + l15][kl];
            #pragma unroll
            for (int n = 0; n < 4; ++n) b[n] = *(const bf16x8*)&Bs[wn * 64 + n * 16 + l15][kl];
            #pragma unroll
            for (int m = 0; m < 4; ++m)
                #pragma unroll
                for (int n = 0; n < 4; ++n)
                    acc[m][n] = __builtin_amdgcn_mfma_f32_16x16x32_bf16(a[m], b[n], acc[m][n], 0, 0, 0);
        }
        __syncthreads();
    }
    #pragma unroll
    for (int m = 0; m < 4; ++m) {
        int rb = wm * 64 + m * 16 + lhi * 4;
        #pragma unroll
        for (int q = 0; q < 4; ++q) {
            int r = rb + q;
            if (row0 + r < ne) {
                int tok = rowTok[r];
                float wgt = rowW[r];
                float* orow = out + (size_t)tok * HD + h0 + wn * 64;
                #pragma unroll
                for (int n = 0; n < 4; ++n)
                    atomicAdd(&orow[n * 16 + l15], acc[m][n][q] * wgt);
            }
        }
    }
}

extern "C" void kernel_launch(void* const* d_in, const int* in_sizes, int n_in,
                              void* d_out, int out_size, void* d_ws, size_t ws_size,
                              hipStream_t stream) {
    const float* x   = (const float*)d_in[0];
    const float* wg  = (const float*)d_in[1];
    const float* wgp = (const float*)d_in[2];
    const float* wup = (const float*)d_in[3];
    const float* wdp = (const float*)d_in[4];
    float* out = (float*)d_out;

    char* ws = (char*)d_ws;
    size_t off = 0;
    unsigned short* X16   = (unsigned short*)(ws + off); off += (size_t)T_TOK * HD * 2;   // 8 MB
    unsigned short* act16 = (unsigned short*)(ws + off); off += (size_t)NPAIR * ID * 2;   // 24 MB
    int*   topk_idx   = (int*)(ws + off);   off += NPAIR * 4;
    float* topk_w     = (float*)(ws + off); off += NPAIR * 4;
    int*   token_list = (int*)(ws + off);   off += NPAIR * 4;
    int*   counts     = (int*)(ws + off);   off += 256;
    int*   offsets    = (int*)(ws + off);   off += 256;
    int*   cursor     = (int*)(ws + off);   off += 256;
    unsigned short* WG = (unsigned short*)(ws + off); off += (size_t)NE * ID * HD * 2;    // 100.7 MB
    unsigned short* WU = (unsigned short*)(ws + off); off += (size_t)NE * ID * HD * 2;
    unsigned short* WD = (unsigned short*)(ws + off); off += (size_t)NE * HD * ID * 2;
    size_t NEEDED = off;
    (void)in_sizes; (void)n_in; (void)out_size;

    hipMemsetAsync(counts, 0, 256, stream);
    hipMemsetAsync(d_out, 0, (size_t)T_TOK * HD * 4, stream);

    cvt_x<<<T_TOK * HD / (256 * 8), 256, 0, stream>>>(x, X16);
    router_kernel<<<T_TOK, 256, 0, stream>>>(x, wg, topk_idx, topk_w, counts);
    offsets_kernel<<<1, 64, 0, stream>>>(counts, offsets, cursor);
    scatter_kernel<<<NPAIR / 256, 256, 0, stream>>>(topk_idx, cursor, token_list);

    if (ws_size >= NEEDED) {
        // pre-transpose + cvt weights: gate/up [H][I]->[I][H], down [I][H]->[H][I]
        transpose_cvt<<<dim3(ID / 64, HD / 64, NE), 256, 0, stream>>>(wgp, WG, HD, ID);
        transpose_cvt<<<dim3(ID / 64, HD / 64, NE), 256, 0, stream>>>(wup, WU, HD, ID);
        transpose_cvt<<<dim3(HD / 64, ID / 64, NE), 256, 0, stream>>>(wdp, WD, ID, HD);
        gemm1_kernel<<<dim3(ID / 128, 16, NE), 256, 0, stream>>>(X16, WG, WU, token_list, counts, offsets, act16);
        gemm2_kernel<<<dim3(HD / 128, 16, NE), 256, 0, stream>>>(act16, WD, token_list, counts, offsets, topk_w, out);
    } else {
        gemm1_fb<<<dim3(ID / 128, 16, NE), 256, 0, stream>>>(X16, wgp, wup, token_list, counts, offsets, act16);
        gemm2_fb<<<dim3(HD / 128, 16, NE), 256, 0, stream>>>(act16, wdp, token_list, counts, offsets, topk_w, out);
    }
}